// Round 10
// baseline (160.249 us; speedup 1.0000x reference)
//
#include <hip/hip_runtime.h>
#include <math.h>

// WHT_expansion: rows of 256 f32 -> pad to 512 -> WHT512 -> pointwise -> WHT512 -> 512 f32.
// R4-champion structure: one row per wave64, TWO rows per loop iteration (loads
// issued back-to-back), ds_swizzle for xor4, DPP for xor1/2/8, permlane swaps
// for bits 4/5. R10 deltas vs R4: (a) regular stores (NT never isolated; fill
// kernel sustains 6.8 TB/s through the L2 write-back path), (b) th-fold: S
// pre-multiplied into th0..3 (4 muls) replacing 8 store-muls per row.
// Ladder history: R5 prefetch −, R6 launch_bounds-force −, R9 DPP-xor4 − (the
// kernel is latency-coupled: +VALU in the serial chain costs ~2.4x its issue).
//   lane xor1/xor2 -> DPP quad_perm (VALU)
//   lane xor8      -> DPP row_ror:8 ((i+8)&15 == i^8)
//   lane xor4      -> ds_swizzle (12 DS/row; fully hidden per R9 A/B)
//   lane xor16/32  -> permlane16/32_swap bit-exchange + register add/sub
// First transform uses H512[x;0] = [H256 x; H256 x] (pad halves duplicate).
// tanh via branchless exp2/rcp (err ~1e-6), f1-scale S folded into exp2 const
// and threshold fma.

#define QP_XOR1  0xB1     // quad_perm [1,0,3,2]
#define QP_XOR2  0x4E     // quad_perm [2,3,0,1]
#define ROR8     0x128    // row_ror:8  (16-lane rows; == xor8)
#define SWZ_XOR4 0x101F   // ds_swizzle BitMode xor=4, and=0x1F

#define DPP_P(v, CTRL) __int_as_float(__builtin_amdgcn_update_dpp( \
    0, __float_as_int(v), CTRL, 0xf, 0xf, false))
#define SWZ_P(v, PAT) __int_as_float(__builtin_amdgcn_ds_swizzle( \
    __float_as_int(v), PAT))
#define BTF(a, b) { float _t = (a); (a) = _t + (b); (b) = _t - (b); }

__device__ __forceinline__ void pl32_swap(float &a, float &b) {
    auto r = __builtin_amdgcn_permlane32_swap(
        (int)__float_as_uint(a), (int)__float_as_uint(b), false, false);
    a = __uint_as_float((unsigned)r[0]);
    b = __uint_as_float((unsigned)r[1]);
}
__device__ __forceinline__ void pl16_swap(float &a, float &b) {
    auto r = __builtin_amdgcn_permlane16_swap(
        (int)__float_as_uint(a), (int)__float_as_uint(b), false, false);
    a = __uint_as_float((unsigned)r[0]);
    b = __uint_as_float((unsigned)r[1]);
}

__global__ __launch_bounds__(256) void wht512_kernel(
    const float* __restrict__ x, const float* __restrict__ T,
    float* __restrict__ y, int nrows)
{
    const int lane = threadIdx.x & 63;
    const int wib  = threadIdx.x >> 6;
    const int wpb  = blockDim.x >> 6;
    const int wave   = blockIdx.x * wpb + wib;
    const int nwaves = gridDim.x * wpb;

    const float S  = 0.044194173824159216f;   // 2^-4.5 = 1/sqrt(512)
    const float S2 = 0.001953125f;            // S^2 = 1/512 (lane-0 passthrough)
    const float K  = -2.885390081777927f * S; // -2*log2(e)*S, folds S into tanh arg

    // signs for lane-bit butterflies: +1 if lane bit clear
    const float sg0 = (lane & 1) ? -1.f : 1.f;
    const float sg1 = (lane & 2) ? -1.f : 1.f;
    const float sg2 = (lane & 4) ? -1.f : 1.f;
    const float sg3 = (lane & 8) ? -1.f : 1.f;

    // |T| hoisted, in the layout present at pointwise time:
    //   element bits: b7=c0, b6=c1, b5..b2 = lane bits 3..0, b1 = lane bit 4, b0 = lane bit 5
    const int tbase = ((lane & 15) << 2) + (((lane >> 4) & 1) << 1) + ((lane >> 5) & 1);
    float Ta[8]; // index = c0 + 2*c1 + 4*h
#pragma unroll
    for (int h = 0; h < 2; ++h)
#pragma unroll
        for (int c1 = 0; c1 < 2; ++c1)
#pragma unroll
            for (int c0 = 0; c0 < 2; ++c0)
                Ta[(h << 2) | (c1 << 1) | c0] =
                    fabsf(T[h * 256 + c0 * 128 + c1 * 64 + tbase]);

    auto do_row = [&](float v0, float v1, float v2, float v3,
                      float4 &o0, float4 &o1) {
        // layout: regs c0=b0, c1=b1; lanes l0..l5 = b2..b7
        // ---- WHT-256 ----
        BTF(v0, v1); BTF(v2, v3);
        BTF(v0, v2); BTF(v1, v3);
        { float p;
          p = DPP_P(v0, QP_XOR1); v0 = fmaf(sg0, v0, p);
          p = DPP_P(v1, QP_XOR1); v1 = fmaf(sg0, v1, p);
          p = DPP_P(v2, QP_XOR1); v2 = fmaf(sg0, v2, p);
          p = DPP_P(v3, QP_XOR1); v3 = fmaf(sg0, v3, p); }
        { float p;
          p = DPP_P(v0, QP_XOR2); v0 = fmaf(sg1, v0, p);
          p = DPP_P(v1, QP_XOR2); v1 = fmaf(sg1, v1, p);
          p = DPP_P(v2, QP_XOR2); v2 = fmaf(sg1, v2, p);
          p = DPP_P(v3, QP_XOR2); v3 = fmaf(sg1, v3, p); }
        { float p;
          p = DPP_P(v0, ROR8); v0 = fmaf(sg3, v0, p);
          p = DPP_P(v1, ROR8); v1 = fmaf(sg3, v1, p);
          p = DPP_P(v2, ROR8); v2 = fmaf(sg3, v2, p);
          p = DPP_P(v3, ROR8); v3 = fmaf(sg3, v3, p); }
        { float p;
          p = SWZ_P(v0, SWZ_XOR4); v0 = fmaf(sg2, v0, p);
          p = SWZ_P(v1, SWZ_XOR4); v1 = fmaf(sg2, v1, p);
          p = SWZ_P(v2, SWZ_XOR4); v2 = fmaf(sg2, v2, p);
          p = SWZ_P(v3, SWZ_XOR4); v3 = fmaf(sg2, v3, p); }
        pl32_swap(v0, v1); pl32_swap(v2, v3);
        pl16_swap(v0, v2); pl16_swap(v1, v3);
        // regs: c0=b7, c1=b6; lanes l4=b1(done), l5=b0(done)
        BTF(v0, v1); BTF(v2, v3);
        BTF(v0, v2); BTF(v1, v3);

        // ---- pointwise (th pre-scaled by S; output WHT then needs no store mul) ----
        const float ab0 = fabsf(v0), ab1 = fabsf(v1), ab2 = fabsf(v2), ab3 = fabsf(v3);
        float t, th0, th1, th2, th3;
        t = __builtin_amdgcn_exp2f(K * ab0);
        th0 = S * copysignf((1.f - t) * __builtin_amdgcn_rcpf(1.f + t), v0);
        t = __builtin_amdgcn_exp2f(K * ab1);
        th1 = S * copysignf((1.f - t) * __builtin_amdgcn_rcpf(1.f + t), v1);
        t = __builtin_amdgcn_exp2f(K * ab2);
        th2 = S * copysignf((1.f - t) * __builtin_amdgcn_rcpf(1.f + t), v2);
        t = __builtin_amdgcn_exp2f(K * ab3);
        th3 = S * copysignf((1.f - t) * __builtin_amdgcn_rcpf(1.f + t), v3);

        float w0 = th0 * fmaxf(fmaf(S, ab0, -Ta[0]), 0.f);
        float w1 = th1 * fmaxf(fmaf(S, ab1, -Ta[1]), 0.f);
        float w2 = th2 * fmaxf(fmaf(S, ab2, -Ta[2]), 0.f);
        float w3 = th3 * fmaxf(fmaf(S, ab3, -Ta[3]), 0.f);
        float w4 = th0 * fmaxf(fmaf(S, ab0, -Ta[4]), 0.f);
        float w5 = th1 * fmaxf(fmaf(S, ab1, -Ta[5]), 0.f);
        float w6 = th2 * fmaxf(fmaf(S, ab2, -Ta[6]), 0.f);
        float w7 = th3 * fmaxf(fmaf(S, ab3, -Ta[7]), 0.f);
        w0 = (lane == 0) ? S2 * v0 : w0;   // f3[0] = f1[0], carries the folded S

        // ---- WHT-512 ----
        // regs: c0=b7, c1=b6, c2=b8; lanes l0..l3=b2..b5, l4=b1, l5=b0
        BTF(w0, w1); BTF(w2, w3); BTF(w4, w5); BTF(w6, w7);
        BTF(w0, w2); BTF(w1, w3); BTF(w4, w6); BTF(w5, w7);
        BTF(w0, w4); BTF(w1, w5); BTF(w2, w6); BTF(w3, w7);
        pl32_swap(w0, w1); pl32_swap(w2, w3); pl32_swap(w4, w5); pl32_swap(w6, w7);
        pl16_swap(w0, w2); pl16_swap(w1, w3); pl16_swap(w4, w6); pl16_swap(w5, w7);
        // regs: c0=b0, c1=b1, c2=b8; lanes l4=b6(done), l5=b7(done)
        BTF(w0, w1); BTF(w2, w3); BTF(w4, w5); BTF(w6, w7);
        BTF(w0, w2); BTF(w1, w3); BTF(w4, w6); BTF(w5, w7);
        { float p;
          p = DPP_P(w0, QP_XOR1); w0 = fmaf(sg0, w0, p);
          p = DPP_P(w1, QP_XOR1); w1 = fmaf(sg0, w1, p);
          p = DPP_P(w2, QP_XOR1); w2 = fmaf(sg0, w2, p);
          p = DPP_P(w3, QP_XOR1); w3 = fmaf(sg0, w3, p);
          p = DPP_P(w4, QP_XOR1); w4 = fmaf(sg0, w4, p);
          p = DPP_P(w5, QP_XOR1); w5 = fmaf(sg0, w5, p);
          p = DPP_P(w6, QP_XOR1); w6 = fmaf(sg0, w6, p);
          p = DPP_P(w7, QP_XOR1); w7 = fmaf(sg0, w7, p); }
        { float p;
          p = DPP_P(w0, QP_XOR2); w0 = fmaf(sg1, w0, p);
          p = DPP_P(w1, QP_XOR2); w1 = fmaf(sg1, w1, p);
          p = DPP_P(w2, QP_XOR2); w2 = fmaf(sg1, w2, p);
          p = DPP_P(w3, QP_XOR2); w3 = fmaf(sg1, w3, p);
          p = DPP_P(w4, QP_XOR2); w4 = fmaf(sg1, w4, p);
          p = DPP_P(w5, QP_XOR2); w5 = fmaf(sg1, w5, p);
          p = DPP_P(w6, QP_XOR2); w6 = fmaf(sg1, w6, p);
          p = DPP_P(w7, QP_XOR2); w7 = fmaf(sg1, w7, p); }
        { float p;
          p = DPP_P(w0, ROR8); w0 = fmaf(sg3, w0, p);
          p = DPP_P(w1, ROR8); w1 = fmaf(sg3, w1, p);
          p = DPP_P(w2, ROR8); w2 = fmaf(sg3, w2, p);
          p = DPP_P(w3, ROR8); w3 = fmaf(sg3, w3, p);
          p = DPP_P(w4, ROR8); w4 = fmaf(sg3, w4, p);
          p = DPP_P(w5, ROR8); w5 = fmaf(sg3, w5, p);
          p = DPP_P(w6, ROR8); w6 = fmaf(sg3, w6, p);
          p = DPP_P(w7, ROR8); w7 = fmaf(sg3, w7, p); }
        { float p;
          p = SWZ_P(w0, SWZ_XOR4); w0 = fmaf(sg2, w0, p);
          p = SWZ_P(w1, SWZ_XOR4); w1 = fmaf(sg2, w1, p);
          p = SWZ_P(w2, SWZ_XOR4); w2 = fmaf(sg2, w2, p);
          p = SWZ_P(w3, SWZ_XOR4); w3 = fmaf(sg2, w3, p);
          p = SWZ_P(w4, SWZ_XOR4); w4 = fmaf(sg2, w4, p);
          p = SWZ_P(w5, SWZ_XOR4); w5 = fmaf(sg2, w5, p);
          p = SWZ_P(w6, SWZ_XOR4); w6 = fmaf(sg2, w6, p);
          p = SWZ_P(w7, SWZ_XOR4); w7 = fmaf(sg2, w7, p); }

        // final layout: i = c2*256 + lane*4 + (c1*2 + c0); reg order == quad order
        o0 = make_float4(w0, w1, w2, w3);
        o1 = make_float4(w4, w5, w6, w7);
    };

    const int half = nrows >> 1;
    for (int r2 = wave; r2 < half; r2 += nwaves) {
        const int rowA = 2 * r2, rowB = rowA + 1;
        // issue both loads up front (2 KB in flight per wave)
        const float4 xa = *reinterpret_cast<const float4*>(x + (size_t)rowA * 256 + 4 * lane);
        const float4 xb = *reinterpret_cast<const float4*>(x + (size_t)rowB * 256 + 4 * lane);

        float4 a0, a1, b0, b1;
        do_row(xa.x, xa.y, xa.z, xa.w, a0, a1);
        {
            const size_t obase = (size_t)rowA * 512 + 4 * lane;
            *reinterpret_cast<float4*>(y + obase) = a0;
            *reinterpret_cast<float4*>(y + obase + 256) = a1;
        }
        do_row(xb.x, xb.y, xb.z, xb.w, b0, b1);
        {
            const size_t obase = (size_t)rowB * 512 + 4 * lane;
            *reinterpret_cast<float4*>(y + obase) = b0;
            *reinterpret_cast<float4*>(y + obase + 256) = b1;
        }
    }
}

extern "C" void kernel_launch(void* const* d_in, const int* in_sizes, int n_in,
                              void* d_out, int out_size, void* d_ws, size_t ws_size,
                              hipStream_t stream) {
    const float* x = (const float*)d_in[0];
    const float* T = (const float*)d_in[1];
    float* y = (float*)d_out;

    const int nrows = in_sizes[0] / 256;   // 262144 rows
    const int block = 256;                  // 4 waves per block
    const int grid  = 2048;                 // grid-stride, 2 rows per wave-iter

    hipLaunchKernelGGL(wht512_kernel, dim3(grid), dim3(block), 0, stream,
                       x, T, y, nrows);
}

// Round 11
// 136.312 us; speedup vs baseline: 1.1756x; 1.1756x over previous
//
#include <hip/hip_runtime.h>
#include <math.h>

// WHT_expansion: rows of 256 f32 -> pad to 512 -> WHT512 -> pointwise -> WHT512 -> 512 f32.
// CHAMPION (R4) structure + th-fold. One row per wave64, TWO rows per loop
// iteration (loads issued back-to-back), NT stores (R10 A/B: regular stores
// +23 us — write-once output must bypass L2/L3), ds_swizzle xor4 (R9 A/B:
// DPP-compose +12 us), natural VGPR (R6: launch_bounds force spilled, +31 us),
// no manual prefetch (R5: +5 us).
//   lane xor1/xor2 -> DPP quad_perm (VALU)
//   lane xor8      -> DPP row_ror:8 ((i+8)&15 == i^8)
//   lane xor4      -> ds_swizzle (12 DS/row; fully hidden per R9 A/B)
//   lane xor16/32  -> permlane16/32_swap bit-exchange + register add/sub
// First transform uses H512[x;0] = [H256 x; H256 x] (pad halves duplicate).
// tanh via branchless exp2/rcp (err ~1e-6); f1-scale S folded into exp2 const,
// threshold fma, and th (th-fold: 4 muls replace 8 store-muls per row).

#define QP_XOR1  0xB1     // quad_perm [1,0,3,2]
#define QP_XOR2  0x4E     // quad_perm [2,3,0,1]
#define ROR8     0x128    // row_ror:8  (16-lane rows; == xor8)
#define SWZ_XOR4 0x101F   // ds_swizzle BitMode xor=4, and=0x1F

#define DPP_P(v, CTRL) __int_as_float(__builtin_amdgcn_update_dpp( \
    0, __float_as_int(v), CTRL, 0xf, 0xf, false))
#define SWZ_P(v, PAT) __int_as_float(__builtin_amdgcn_ds_swizzle( \
    __float_as_int(v), PAT))
#define BTF(a, b) { float _t = (a); (a) = _t + (b); (b) = _t - (b); }

typedef float f32x4 __attribute__((ext_vector_type(4)));

__device__ __forceinline__ void pl32_swap(float &a, float &b) {
    auto r = __builtin_amdgcn_permlane32_swap(
        (int)__float_as_uint(a), (int)__float_as_uint(b), false, false);
    a = __uint_as_float((unsigned)r[0]);
    b = __uint_as_float((unsigned)r[1]);
}
__device__ __forceinline__ void pl16_swap(float &a, float &b) {
    auto r = __builtin_amdgcn_permlane16_swap(
        (int)__float_as_uint(a), (int)__float_as_uint(b), false, false);
    a = __uint_as_float((unsigned)r[0]);
    b = __uint_as_float((unsigned)r[1]);
}

__global__ __launch_bounds__(256) void wht512_kernel(
    const float* __restrict__ x, const float* __restrict__ T,
    float* __restrict__ y, int nrows)
{
    const int lane = threadIdx.x & 63;
    const int wib  = threadIdx.x >> 6;
    const int wpb  = blockDim.x >> 6;
    const int wave   = blockIdx.x * wpb + wib;
    const int nwaves = gridDim.x * wpb;

    const float S  = 0.044194173824159216f;   // 2^-4.5 = 1/sqrt(512)
    const float S2 = 0.001953125f;            // S^2 = 1/512 (lane-0 passthrough)
    const float K  = -2.885390081777927f * S; // -2*log2(e)*S, folds S into tanh arg

    // signs for lane-bit butterflies: +1 if lane bit clear
    const float sg0 = (lane & 1) ? -1.f : 1.f;
    const float sg1 = (lane & 2) ? -1.f : 1.f;
    const float sg2 = (lane & 4) ? -1.f : 1.f;
    const float sg3 = (lane & 8) ? -1.f : 1.f;

    // |T| hoisted, in the layout present at pointwise time:
    //   element bits: b7=c0, b6=c1, b5..b2 = lane bits 3..0, b1 = lane bit 4, b0 = lane bit 5
    const int tbase = ((lane & 15) << 2) + (((lane >> 4) & 1) << 1) + ((lane >> 5) & 1);
    float Ta[8]; // index = c0 + 2*c1 + 4*h
#pragma unroll
    for (int h = 0; h < 2; ++h)
#pragma unroll
        for (int c1 = 0; c1 < 2; ++c1)
#pragma unroll
            for (int c0 = 0; c0 < 2; ++c0)
                Ta[(h << 2) | (c1 << 1) | c0] =
                    fabsf(T[h * 256 + c0 * 128 + c1 * 64 + tbase]);

    auto do_row = [&](float v0, float v1, float v2, float v3,
                      f32x4 &o0, f32x4 &o1) {
        // layout: regs c0=b0, c1=b1; lanes l0..l5 = b2..b7
        // ---- WHT-256 ----
        BTF(v0, v1); BTF(v2, v3);
        BTF(v0, v2); BTF(v1, v3);
        { float p;
          p = DPP_P(v0, QP_XOR1); v0 = fmaf(sg0, v0, p);
          p = DPP_P(v1, QP_XOR1); v1 = fmaf(sg0, v1, p);
          p = DPP_P(v2, QP_XOR1); v2 = fmaf(sg0, v2, p);
          p = DPP_P(v3, QP_XOR1); v3 = fmaf(sg0, v3, p); }
        { float p;
          p = DPP_P(v0, QP_XOR2); v0 = fmaf(sg1, v0, p);
          p = DPP_P(v1, QP_XOR2); v1 = fmaf(sg1, v1, p);
          p = DPP_P(v2, QP_XOR2); v2 = fmaf(sg1, v2, p);
          p = DPP_P(v3, QP_XOR2); v3 = fmaf(sg1, v3, p); }
        { float p;
          p = DPP_P(v0, ROR8); v0 = fmaf(sg3, v0, p);
          p = DPP_P(v1, ROR8); v1 = fmaf(sg3, v1, p);
          p = DPP_P(v2, ROR8); v2 = fmaf(sg3, v2, p);
          p = DPP_P(v3, ROR8); v3 = fmaf(sg3, v3, p); }
        { float p;
          p = SWZ_P(v0, SWZ_XOR4); v0 = fmaf(sg2, v0, p);
          p = SWZ_P(v1, SWZ_XOR4); v1 = fmaf(sg2, v1, p);
          p = SWZ_P(v2, SWZ_XOR4); v2 = fmaf(sg2, v2, p);
          p = SWZ_P(v3, SWZ_XOR4); v3 = fmaf(sg2, v3, p); }
        pl32_swap(v0, v1); pl32_swap(v2, v3);
        pl16_swap(v0, v2); pl16_swap(v1, v3);
        // regs: c0=b7, c1=b6; lanes l4=b1(done), l5=b0(done)
        BTF(v0, v1); BTF(v2, v3);
        BTF(v0, v2); BTF(v1, v3);

        // ---- pointwise (th pre-scaled by S; output needs no store mul) ----
        const float ab0 = fabsf(v0), ab1 = fabsf(v1), ab2 = fabsf(v2), ab3 = fabsf(v3);
        float t, th0, th1, th2, th3;
        t = __builtin_amdgcn_exp2f(K * ab0);
        th0 = S * copysignf((1.f - t) * __builtin_amdgcn_rcpf(1.f + t), v0);
        t = __builtin_amdgcn_exp2f(K * ab1);
        th1 = S * copysignf((1.f - t) * __builtin_amdgcn_rcpf(1.f + t), v1);
        t = __builtin_amdgcn_exp2f(K * ab2);
        th2 = S * copysignf((1.f - t) * __builtin_amdgcn_rcpf(1.f + t), v2);
        t = __builtin_amdgcn_exp2f(K * ab3);
        th3 = S * copysignf((1.f - t) * __builtin_amdgcn_rcpf(1.f + t), v3);

        float w0 = th0 * fmaxf(fmaf(S, ab0, -Ta[0]), 0.f);
        float w1 = th1 * fmaxf(fmaf(S, ab1, -Ta[1]), 0.f);
        float w2 = th2 * fmaxf(fmaf(S, ab2, -Ta[2]), 0.f);
        float w3 = th3 * fmaxf(fmaf(S, ab3, -Ta[3]), 0.f);
        float w4 = th0 * fmaxf(fmaf(S, ab0, -Ta[4]), 0.f);
        float w5 = th1 * fmaxf(fmaf(S, ab1, -Ta[5]), 0.f);
        float w6 = th2 * fmaxf(fmaf(S, ab2, -Ta[6]), 0.f);
        float w7 = th3 * fmaxf(fmaf(S, ab3, -Ta[7]), 0.f);
        w0 = (lane == 0) ? S2 * v0 : w0;   // f3[0] = f1[0], carries the folded S

        // ---- WHT-512 ----
        // regs: c0=b7, c1=b6, c2=b8; lanes l0..l3=b2..b5, l4=b1, l5=b0
        BTF(w0, w1); BTF(w2, w3); BTF(w4, w5); BTF(w6, w7);
        BTF(w0, w2); BTF(w1, w3); BTF(w4, w6); BTF(w5, w7);
        BTF(w0, w4); BTF(w1, w5); BTF(w2, w6); BTF(w3, w7);
        pl32_swap(w0, w1); pl32_swap(w2, w3); pl32_swap(w4, w5); pl32_swap(w6, w7);
        pl16_swap(w0, w2); pl16_swap(w1, w3); pl16_swap(w4, w6); pl16_swap(w5, w7);
        // regs: c0=b0, c1=b1, c2=b8; lanes l4=b6(done), l5=b7(done)
        BTF(w0, w1); BTF(w2, w3); BTF(w4, w5); BTF(w6, w7);
        BTF(w0, w2); BTF(w1, w3); BTF(w4, w6); BTF(w5, w7);
        { float p;
          p = DPP_P(w0, QP_XOR1); w0 = fmaf(sg0, w0, p);
          p = DPP_P(w1, QP_XOR1); w1 = fmaf(sg0, w1, p);
          p = DPP_P(w2, QP_XOR1); w2 = fmaf(sg0, w2, p);
          p = DPP_P(w3, QP_XOR1); w3 = fmaf(sg0, w3, p);
          p = DPP_P(w4, QP_XOR1); w4 = fmaf(sg0, w4, p);
          p = DPP_P(w5, QP_XOR1); w5 = fmaf(sg0, w5, p);
          p = DPP_P(w6, QP_XOR1); w6 = fmaf(sg0, w6, p);
          p = DPP_P(w7, QP_XOR1); w7 = fmaf(sg0, w7, p); }
        { float p;
          p = DPP_P(w0, QP_XOR2); w0 = fmaf(sg1, w0, p);
          p = DPP_P(w1, QP_XOR2); w1 = fmaf(sg1, w1, p);
          p = DPP_P(w2, QP_XOR2); w2 = fmaf(sg1, w2, p);
          p = DPP_P(w3, QP_XOR2); w3 = fmaf(sg1, w3, p);
          p = DPP_P(w4, QP_XOR2); w4 = fmaf(sg1, w4, p);
          p = DPP_P(w5, QP_XOR2); w5 = fmaf(sg1, w5, p);
          p = DPP_P(w6, QP_XOR2); w6 = fmaf(sg1, w6, p);
          p = DPP_P(w7, QP_XOR2); w7 = fmaf(sg1, w7, p); }
        { float p;
          p = DPP_P(w0, ROR8); w0 = fmaf(sg3, w0, p);
          p = DPP_P(w1, ROR8); w1 = fmaf(sg3, w1, p);
          p = DPP_P(w2, ROR8); w2 = fmaf(sg3, w2, p);
          p = DPP_P(w3, ROR8); w3 = fmaf(sg3, w3, p);
          p = DPP_P(w4, ROR8); w4 = fmaf(sg3, w4, p);
          p = DPP_P(w5, ROR8); w5 = fmaf(sg3, w5, p);
          p = DPP_P(w6, ROR8); w6 = fmaf(sg3, w6, p);
          p = DPP_P(w7, ROR8); w7 = fmaf(sg3, w7, p); }
        { float p;
          p = SWZ_P(w0, SWZ_XOR4); w0 = fmaf(sg2, w0, p);
          p = SWZ_P(w1, SWZ_XOR4); w1 = fmaf(sg2, w1, p);
          p = SWZ_P(w2, SWZ_XOR4); w2 = fmaf(sg2, w2, p);
          p = SWZ_P(w3, SWZ_XOR4); w3 = fmaf(sg2, w3, p);
          p = SWZ_P(w4, SWZ_XOR4); w4 = fmaf(sg2, w4, p);
          p = SWZ_P(w5, SWZ_XOR4); w5 = fmaf(sg2, w5, p);
          p = SWZ_P(w6, SWZ_XOR4); w6 = fmaf(sg2, w6, p);
          p = SWZ_P(w7, SWZ_XOR4); w7 = fmaf(sg2, w7, p); }

        // final layout: i = c2*256 + lane*4 + (c1*2 + c0); reg order == quad order
        o0 = (f32x4){w0, w1, w2, w3};
        o1 = (f32x4){w4, w5, w6, w7};
    };

    const int half = nrows >> 1;
    for (int r2 = wave; r2 < half; r2 += nwaves) {
        const int rowA = 2 * r2, rowB = rowA + 1;
        // issue both loads up front (2 KB in flight per wave)
        const float4 xa = *reinterpret_cast<const float4*>(x + (size_t)rowA * 256 + 4 * lane);
        const float4 xb = *reinterpret_cast<const float4*>(x + (size_t)rowB * 256 + 4 * lane);

        f32x4 a0, a1, b0, b1;
        do_row(xa.x, xa.y, xa.z, xa.w, a0, a1);
        {
            const size_t obase = (size_t)rowA * 512 + 4 * lane;
            __builtin_nontemporal_store(a0, reinterpret_cast<f32x4*>(y + obase));
            __builtin_nontemporal_store(a1, reinterpret_cast<f32x4*>(y + obase + 256));
        }
        do_row(xb.x, xb.y, xb.z, xb.w, b0, b1);
        {
            const size_t obase = (size_t)rowB * 512 + 4 * lane;
            __builtin_nontemporal_store(b0, reinterpret_cast<f32x4*>(y + obase));
            __builtin_nontemporal_store(b1, reinterpret_cast<f32x4*>(y + obase + 256));
        }
    }
}

extern "C" void kernel_launch(void* const* d_in, const int* in_sizes, int n_in,
                              void* d_out, int out_size, void* d_ws, size_t ws_size,
                              hipStream_t stream) {
    const float* x = (const float*)d_in[0];
    const float* T = (const float*)d_in[1];
    float* y = (float*)d_out;

    const int nrows = in_sizes[0] / 256;   // 262144 rows
    const int block = 256;                  // 4 waves per block
    const int grid  = 2048;                 // grid-stride, 2 rows per wave-iter

    hipLaunchKernelGGL(wht512_kernel, dim3(grid), dim3(block), 0, stream,
                       x, T, y, nrows);
}